// Round 6
// baseline (211.728 us; speedup 1.0000x reference)
//
#include <hip/hip_runtime.h>

// ---------------------------------------------------------------------------
// SphericalExpansion: ci[i,s,n,lm] = sum_{e: idx_i[e]==i, z[idx_j[e]]==s}
//                       fc(d_e) * (sum_k g_k(d_e) W[l(lm),n,k]) * Y_lm(dir_e)
// N_EDGES=800000, N_ATOMS=20000, NMAX=8, LM=16, N_SPECIES=4
//
// R5 design (resubmitted R6 — GPU timeout, never benched):
//  R4 measured: k_main 79us (FETCH 121->8MB fix confirmed); scatter phase
//  ~120us UNCHANGED vs R3 despite cursor padding + 16B stores => cost is
//  random 64B line touches / atomics, not line ping-pong. Fixes:
//   1) k_prep: records in EDGE order (coalesced R+W) - removes 41MB random
//      store region. k_scatter_id scatters only 4B ids into 10.2MB region
//      (better L2/L3 residency for write-allocate RMW). Split => rocprof rows.
//   2) k_main: ids contiguous + 16B rec gathers (L3-resident 12.8MB);
//      8 edges/wave-iter + 2-deep prefetch pipeline (recs & ids).
//      Wave-independent (zero block barriers in loop).
// ---------------------------------------------------------------------------

#define NMAXC   8
#define LMC     16
#define NSPECC  4
#define RCUT    5.0f
#define RIN_    4.5f      // RC - SMOOTH_WIDTH
#define PI_F    3.14159265358979323846f
#define CAP     128       // bucket capacity (Poisson(40) tail ~1e-28)
#define CPAD    16        // cursor padding in ints (64B/line)

// Ylm = C[lm] * A * B;  A: 0->1, 1->x, 2->y, 3->z, 4->xy
// B: 0->1, 1->z, 2->3z2-1, 3->x2-y2, 4->3x2-y2, 5->5z2-1, 6->5z2-3, 7->x2-3y2
__device__ const int   d_Asel[16] = {0,2,3,1,4,2,0,1,0,2,4,2,3,1,3,1};
__device__ const int   d_Bsel[16] = {0,0,0,0,0,1,2,1,3,4,1,5,6,5,3,7};
__device__ const float d_Clm[16]  = {
    0.28209479177387814f, 0.4886025119029199f, 0.4886025119029199f,
    0.4886025119029199f,  1.0925484305920792f, 1.0925484305920792f,
    0.31539156525252005f, 1.0925484305920792f, 0.5462742152960396f,
    0.5900435899266435f,  2.890611442640554f,  0.4570457994644658f,
    0.3731763325901154f,  0.4570457994644658f, 1.445305721320277f,
    0.5900435899266435f };

__device__ __forceinline__ float ylm_eval(int asel, int bsel, float c_lm,
                                          float x, float y, float zz) {
    float x2 = x * x, y2 = y * y, z2 = zz * zz;
    float A = (asel == 0) ? 1.0f :
              (asel == 1) ? x    :
              (asel == 2) ? y    :
              (asel == 3) ? zz   : x * y;
    float B = (bsel == 0) ? 1.0f :
              (bsel == 1) ? zz   :
              (bsel == 2) ? fmaf(3.0f, z2, -1.0f) :
              (bsel == 3) ? (x2 - y2)             :
              (bsel == 4) ? fmaf(3.0f, x2, -y2)   :
              (bsel == 5) ? fmaf(5.0f, z2, -1.0f) :
              (bsel == 6) ? fmaf(5.0f, z2, -3.0f) :
                            fmaf(-3.0f, y2, x2);
    return c_lm * A * B;
}

// ---------------- prep: records in EDGE order (fully coalesced) ------------
__global__ void k_prep(const float* __restrict__ dist,
                       const float* __restrict__ dirs,
                       const int* __restrict__ zarr,
                       const int* __restrict__ idx_j,
                       float4* __restrict__ recs, int n_edges) {
    int e = blockIdx.x * blockDim.x + threadIdx.x;
    if (e >= n_edges) return;
    float d = dist[e];
    float x = dirs[3 * e + 0], y = dirs[3 * e + 1], zz = dirs[3 * e + 2];
    int s = zarr[idx_j[e]] & 3;                               // z: 80KB, L2-hit
    unsigned db = (__float_as_uint(d) & ~3u) | (unsigned)s;   // <=2^-22 perturb
    float4 r; r.x = __uint_as_float(db); r.y = x; r.z = y; r.w = zz;
    recs[e] = r;
}

// ---------------- id scatter into fixed-cap buckets (T1) -------------------
__global__ void k_scatter_id(const int* __restrict__ idx_i,
                             int* __restrict__ cursors_p,
                             int* __restrict__ ids, int n_edges) {
    int e = blockIdx.x * blockDim.x + threadIdx.x;
    if (e >= n_edges) return;
    int a = idx_i[e];
    int c = atomicAdd(&cursors_p[a * CPAD], 1);
    if (c < CAP) ids[a * CAP + c] = e;
}

// ---------------- CSR-exact path (T2) --------------------------------------
__global__ void k_count_p(const int* __restrict__ idx_i, int* __restrict__ counts_p,
                          int n_edges) {
    int e = blockIdx.x * blockDim.x + threadIdx.x;
    if (e < n_edges) atomicAdd(&counts_p[idx_i[e] * CPAD], 1);
}

__global__ __launch_bounds__(1024) void k_scan_p(const int* __restrict__ counts_p,
                                                 int* __restrict__ offsets,
                                                 int* __restrict__ cursors_p, int n) {
    __shared__ int wsum[16];
    __shared__ int carry_s;
    int t = threadIdx.x;
    int lane = t & 63, w = t >> 6;
    if (t == 0) carry_s = 0;
    __syncthreads();
    for (int base = 0; base < n; base += 1024) {
        int i = base + t;
        int v = (i < n) ? counts_p[i * CPAD] : 0;
        int x = v;
        #pragma unroll
        for (int off = 1; off < 64; off <<= 1) {
            int y = __shfl_up(x, off);
            if (lane >= off) x += y;
        }
        if (lane == 63) wsum[w] = x;
        __syncthreads();
        if (w == 0) {
            int ws = (lane < 16) ? wsum[lane] : 0;
            #pragma unroll
            for (int off = 1; off < 16; off <<= 1) {
                int y = __shfl_up(ws, off);
                if (lane >= off) ws += y;
            }
            if (lane < 16) wsum[lane] = ws;
        }
        __syncthreads();
        int wbase = (w > 0) ? wsum[w - 1] : 0;
        int inc = wbase + x;
        int carry = carry_s;
        if (i < n) {
            int exc = carry + inc - v;
            offsets[i] = exc;
            cursors_p[i * CPAD] = exc;
        }
        __syncthreads();
        if (t == 1023) carry_s = carry + inc;
        __syncthreads();
    }
}

__global__ void k_scatter_id_csr(const int* __restrict__ idx_i,
                                 int* __restrict__ cursors_p,
                                 int* __restrict__ ids, int n_edges) {
    int e = blockIdx.x * blockDim.x + threadIdx.x;
    if (e >= n_edges) return;
    int pos = atomicAdd(&cursors_p[idx_i[e] * CPAD], 1);
    ids[pos] = e;
}

// ---------------- main per-atom kernel -------------------------------------
// 128 thr = 2 independent waves; wave handles 8 edges/iter, stride 16.
// 2-deep pipeline: recs for iter+1 and ids for iter+2 prefetched.
__global__ __launch_bounds__(128) void k_main(
        const float4* __restrict__ recs, const int* __restrict__ ids_all,
        const float* __restrict__ W, const float* __restrict__ centers,
        const int* __restrict__ cnts_p, const int* __restrict__ offsets,
        float* __restrict__ out) {
    const int atom = blockIdx.x;
    const int t = threadIdx.x;
    const int w = t >> 6, L = t & 63;
    const int lm = L & 15, g = L >> 4;      // g: edge group 0..3 (= n0 in stage3)
    const int l  = (lm >= 9) ? 3 : (lm >= 4) ? 2 : (lm >= 1) ? 1 : 0;
    const int r0 = l * 8 + g;               // rin index (n-slot 0); slot1 = r0+4
    const int row = L & 31, p = L >> 5;     // stage2: W row; edges p,p+2,p+4,p+6

    const float ck   = centers[lm];
    const float c_lm = d_Clm[lm];
    const int   asel = d_Asel[lm], bsel = d_Bsel[lm];
    const float4* wp = reinterpret_cast<const float4*>(W + (row << 4));
    const float4 w0 = wp[0], w1 = wp[1], w2 = wp[2], w3 = wp[3];

    __shared__ float ggfc[2][8][16];        // [wave][edge][k]
    __shared__ float ylmS[2][8][16];
    __shared__ float rinS[2][8][32];
    __shared__ int   msS [2][8];
    __shared__ float red [2][8][64];

    int cnt = cnts_p[atom * CPAD];
    const int* idsp;
    if (offsets) { idsp = ids_all + offsets[atom]; }
    else { idsp = ids_all + (size_t)atom * CAP; if (cnt > CAP) cnt = CAP; }

    float a00=0.f,a01=0.f,a10=0.f,a11=0.f,a20=0.f,a21=0.f,a30=0.f,a31=0.f;

    if (cnt > 0) {
        int base = w * 8;
        int sA = base + g, sB = sA + 4;
        bool vA = sA < cnt, vB = sB < cnt;
        int iA = idsp[vA ? sA : 0];
        int iB = idsp[vB ? sB : 0];
        int sA1 = sA + 16, sB1 = sB + 16;
        bool vA1 = sA1 < cnt, vB1 = sB1 < cnt;
        int iA1 = idsp[vA1 ? sA1 : 0];
        int iB1 = idsp[vB1 ? sB1 : 0];
        float4 rA = recs[iA], rB = recs[iB];

        for (; base < cnt; base += 16) {
            // prefetch: recs for iter+1, ids for iter+2
            float4 rAn = recs[iA1], rBn = recs[iB1];
            int sA2 = sA + 32, sB2 = sB + 32;
            bool vA2 = sA2 < cnt, vB2 = sB2 < cnt;
            int iA2 = idsp[vA2 ? sA2 : 0];
            int iB2 = idsp[vB2 ? sB2 : 0];

            // ---- stage 1: g*fc + Ylm for edges g and g+4 ----
            {
                float d = rA.x, x = rA.y, y = rA.z, zz = rA.w;
                int spec = __float_as_uint(d) & 3;
                float tt = fminf(fmaxf((d - RIN_) * 2.0f, 0.0f), 1.0f);
                float fcv = 0.5f * (__cosf(PI_F * tt) + 1.0f);
                float dd = d - ck;
                float gv = __expf(-2.0f * dd * dd) * fcv;
                gv = vA ? gv : 0.0f;
                float yv = ylm_eval(asel, bsel, c_lm, x, y, zz);
                yv = vA ? yv : 0.0f;
                ggfc[w][g][lm] = gv; ylmS[w][g][lm] = yv;
                if (lm == 0) msS[w][g] = spec;
            }
            {
                float d = rB.x, x = rB.y, y = rB.z, zz = rB.w;
                int spec = __float_as_uint(d) & 3;
                float tt = fminf(fmaxf((d - RIN_) * 2.0f, 0.0f), 1.0f);
                float fcv = 0.5f * (__cosf(PI_F * tt) + 1.0f);
                float dd = d - ck;
                float gv = __expf(-2.0f * dd * dd) * fcv;
                gv = vB ? gv : 0.0f;
                float yv = ylm_eval(asel, bsel, c_lm, x, y, zz);
                yv = vB ? yv : 0.0f;
                ggfc[w][g + 4][lm] = gv; ylmS[w][g + 4][lm] = yv;
                if (lm == 0) msS[w][g + 4] = spec;
            }
            __builtin_amdgcn_wave_barrier();
            // ---- stage 2: RIln, 4 dot16 per lane (edges p,p+2,p+4,p+6) ----
            #pragma unroll
            for (int q = 0; q < 4; ++q) {
                int e = p + 2 * q;
                const float4* ga = reinterpret_cast<const float4*>(&ggfc[w][e][0]);
                float4 A0 = ga[0], A1 = ga[1], A2 = ga[2], A3 = ga[3];
                float r = A0.x * w0.x;
                r = fmaf(A0.y, w0.y, r); r = fmaf(A0.z, w0.z, r); r = fmaf(A0.w, w0.w, r);
                r = fmaf(A1.x, w1.x, r); r = fmaf(A1.y, w1.y, r); r = fmaf(A1.z, w1.z, r); r = fmaf(A1.w, w1.w, r);
                r = fmaf(A2.x, w2.x, r); r = fmaf(A2.y, w2.y, r); r = fmaf(A2.z, w2.z, r); r = fmaf(A2.w, w2.w, r);
                r = fmaf(A3.x, w3.x, r); r = fmaf(A3.y, w3.y, r); r = fmaf(A3.z, w3.z, r); r = fmaf(A3.w, w3.w, r);
                rinS[w][e][row] = r;
            }
            __builtin_amdgcn_wave_barrier();
            // ---- stage 3: accumulate 8 edges ----
            #pragma unroll
            for (int e = 0; e < 8; ++e) {
                float ye = ylmS[w][e][lm];
                float va = rinS[w][e][r0];
                float vb = rinS[w][e][r0 + 4];
                int s = __builtin_amdgcn_readfirstlane(msS[w][e]);  // wave-uniform
                float v0 = va * ye, v1 = vb * ye;
                if (s == 0)      { a00 += v0; a01 += v1; }
                else if (s == 1) { a10 += v0; a11 += v1; }
                else if (s == 2) { a20 += v0; a21 += v1; }
                else             { a30 += v0; a31 += v1; }
            }
            __builtin_amdgcn_wave_barrier();

            rA = rAn; rB = rBn;
            vA = vA1; vB = vB1;
            sA = sA1; sB = sB1;
            sA1 = sA2; sB1 = sB2; vA1 = vA2; vB1 = vB2; iA1 = iA2; iB1 = iB2;
        }
    }

    // ---- cross-wave reduce + coalesced store ----
    red[w][0][L] = a00; red[w][1][L] = a01;
    red[w][2][L] = a10; red[w][3][L] = a11;
    red[w][4][L] = a20; red[w][5][L] = a21;
    red[w][6][L] = a30; red[w][7][L] = a31;
    __syncthreads();
    const int h = t >> 6, Ls = t & 63;
    float* ob = out + (size_t)atom * (NSPECC * NMAXC * LMC);
    #pragma unroll
    for (int s = 0; s < 4; ++s)
        ob[s * 128 + t] = red[0][s * 2 + h][Ls] + red[1][s * 2 + h][Ls];
}

// ---------------- last-resort fallback: direct atomics ---------------------
__device__ __forceinline__ float cutoff_fn(float d) {
    float tt = (d - RIN_) * 2.0f;
    tt = fminf(fmaxf(tt, 0.0f), 1.0f);
    float ramp = 0.5f * (cosf(PI_F * tt) + 1.0f);
    return (d < RCUT) ? ramp : 0.0f;
}

__global__ __launch_bounds__(128) void k_atomic(
        const float* __restrict__ distances, const float* __restrict__ dirs,
        const float* __restrict__ W, const float* __restrict__ centers,
        const int* __restrict__ zarr, const int* __restrict__ idx_i,
        const int* __restrict__ idx_j, float* __restrict__ out, int n_edges) {
    const int t = threadIdx.x;
    const int n = t >> 4, lm = t & 15;
    const int base = blockIdx.x * 8;

    __shared__ float4 gbuf[8][4];
    __shared__ float  ylm[8][16];
    __shared__ float  md[8], mfc[8], mx[8], my[8], mz[8];
    __shared__ int    ms[8], mi[8];

    const int l = (lm >= 9) ? 3 : (lm >= 4) ? 2 : (lm >= 1) ? 1 : 0;
    const float4* wp = reinterpret_cast<const float4*>(W + ((l * NMAXC + n) << 4));
    const float4 w0 = wp[0], w1 = wp[1], w2 = wp[2], w3 = wp[3];
    const float ck = centers[lm];

    if (t < 8) {
        int e = base + t;
        if (e < n_edges) {
            float d = distances[e];
            md[t] = d; mfc[t] = cutoff_fn(d);
            mx[t] = dirs[3 * e + 0];
            my[t] = dirs[3 * e + 1];
            mz[t] = dirs[3 * e + 2];
            ms[t] = zarr[idx_j[e]];
            mi[t] = idx_i[e];
        } else {
            md[t] = 1e9f; mfc[t] = 0.f;
            mx[t] = 0.f; my[t] = 0.f; mz[t] = 0.f; ms[t] = 0; mi[t] = 0;
        }
    }
    __syncthreads();
    {
        int e = t >> 4;
        float dd = md[e] - ck;
        reinterpret_cast<float*>(&gbuf[e][0])[lm] = __expf(-2.0f * dd * dd) * mfc[e];
    }
    {
        int e2 = t & 7, lm2 = t >> 3;
        ylm[e2][lm2] = ylm_eval(d_Asel[lm2], d_Bsel[lm2], d_Clm[lm2],
                                mx[e2], my[e2], mz[e2]);
    }
    __syncthreads();
    #pragma unroll
    for (int e = 0; e < 8; ++e) {
        float4 a0 = gbuf[e][0], a1 = gbuf[e][1], a2 = gbuf[e][2], a3 = gbuf[e][3];
        float r;
        r = a0.x * w0.x;
        r = fmaf(a0.y, w0.y, r); r = fmaf(a0.z, w0.z, r); r = fmaf(a0.w, w0.w, r);
        r = fmaf(a1.x, w1.x, r); r = fmaf(a1.y, w1.y, r); r = fmaf(a1.z, w1.z, r); r = fmaf(a1.w, w1.w, r);
        r = fmaf(a2.x, w2.x, r); r = fmaf(a2.y, w2.y, r); r = fmaf(a2.z, w2.z, r); r = fmaf(a2.w, w2.w, r);
        r = fmaf(a3.x, w3.x, r); r = fmaf(a3.y, w3.y, r); r = fmaf(a3.z, w3.z, r); r = fmaf(a3.w, w3.w, r);
        float v = r * ylm[e][lm];
        int target = (mi[e] * NSPECC + ms[e]) * (NMAXC * LMC) + t;
        unsafeAtomicAdd(&out[target], v);
    }
}

// ---------------------------------------------------------------------------
extern "C" void kernel_launch(void* const* d_in, const int* in_sizes, int n_in,
                              void* d_out, int out_size, void* d_ws, size_t ws_size,
                              hipStream_t stream) {
    const float* distances = (const float*)d_in[0];
    const float* dirs      = (const float*)d_in[1];
    const float* W         = (const float*)d_in[2];
    const float* centers   = (const float*)d_in[3];
    const int*   zarr      = (const int*)d_in[4];
    const int*   idx_i     = (const int*)d_in[5];
    const int*   idx_j     = (const int*)d_in[6];
    float*       out       = (float*)d_out;

    const int n_edges = in_sizes[0];
    const int n_atoms = in_sizes[4];
    const int eb = (n_edges + 255) / 256;

    const size_t curs_b = (size_t)n_atoms * CPAD * sizeof(int);          // 1.28MB
    const size_t recs_b = (size_t)n_edges * sizeof(float4);              // 12.8MB
    const size_t ids1_b = (size_t)n_atoms * CAP * sizeof(int);           // 10.24MB
    const size_t ids2_b = (size_t)n_edges * sizeof(int);                 // 3.2MB
    const size_t offs_b = (size_t)n_atoms * sizeof(int);

    const size_t need_t1 = curs_b + ids1_b + recs_b + 64;
    const size_t need_t2 = 2 * curs_b + offs_b + ids2_b + recs_b + 64;

    if (ws_size >= need_t1) {
        // T1: fixed-cap id buckets + edge-order records
        int*    cursors_p = (int*)d_ws;
        int*    ids       = (int*)((char*)d_ws + curs_b);
        float4* recs      = (float4*)((char*)d_ws + curs_b + ids1_b);
        hipMemsetAsync(cursors_p, 0, curs_b, stream);
        k_prep<<<eb, 256, 0, stream>>>(distances, dirs, zarr, idx_j, recs, n_edges);
        k_scatter_id<<<eb, 256, 0, stream>>>(idx_i, cursors_p, ids, n_edges);
        k_main<<<n_atoms, 128, 0, stream>>>(recs, ids, W, centers, cursors_p,
                                            nullptr, out);
    } else if (ws_size >= need_t2) {
        // T2: CSR-exact ids (count -> scan -> scatter) + edge-order records
        int*    counts_p  = (int*)d_ws;
        int*    cursors_p = (int*)((char*)d_ws + curs_b);
        int*    offsets   = (int*)((char*)d_ws + 2 * curs_b);
        int*    ids       = (int*)((char*)d_ws + 2 * curs_b + offs_b);
        float4* recs      = (float4*)((char*)d_ws + 2 * curs_b + offs_b + ids2_b);
        hipMemsetAsync(counts_p, 0, curs_b, stream);
        k_prep<<<eb, 256, 0, stream>>>(distances, dirs, zarr, idx_j, recs, n_edges);
        k_count_p<<<eb, 256, 0, stream>>>(idx_i, counts_p, n_edges);
        k_scan_p<<<1, 1024, 0, stream>>>(counts_p, offsets, cursors_p, n_atoms);
        k_scatter_id_csr<<<eb, 256, 0, stream>>>(idx_i, cursors_p, ids, n_edges);
        k_main<<<n_atoms, 128, 0, stream>>>(recs, ids, W, centers, counts_p,
                                            offsets, out);
    } else {
        // last resort: direct atomics into output
        hipMemsetAsync(out, 0, (size_t)out_size * sizeof(float), stream);
        k_atomic<<<(n_edges + 7) / 8, 128, 0, stream>>>(distances, dirs, W, centers,
                                                        zarr, idx_i, idx_j, out, n_edges);
    }
}

// Round 7
// 205.329 us; speedup vs baseline: 1.0312x; 1.0312x over previous
//
#include <hip/hip_runtime.h>

// ---------------------------------------------------------------------------
// SphericalExpansion. R7 design:
//  Evidence R3/R4/R6: scatter phase ~110-133us invariant to region size,
//  store width, cursor padding => 800K device-scope atomicAdds with 40-way
//  same-address collision chains are the cost (remote-RMW serialization).
//  Fix: SUB=8 sub-cursors per atom (selected by e&7) -> chains of ~5.
//  k_main consumes sub-buckets via register prefix + select-chain mapping.
//  Tiers: A) direct 16B record sub-buckets (82.6MB ws), B) 4B id sub-buckets
//  + edge-order recs (33.9MB), C) flat SUB=1 (R6 replica, 23.1MB), D) atomic.
// ---------------------------------------------------------------------------

#define NMAXC   8
#define LMC     16
#define NSPECC  4
#define RCUT    5.0f
#define RIN_    4.5f
#define PI_F    3.14159265358979323846f

// Ylm = C[lm] * A * B;  A: 0->1, 1->x, 2->y, 3->z, 4->xy
// B: 0->1,1->z,2->3z2-1,3->x2-y2,4->3x2-y2,5->5z2-1,6->5z2-3,7->x2-3y2
__device__ const int   d_Asel[16] = {0,2,3,1,4,2,0,1,0,2,4,2,3,1,3,1};
__device__ const int   d_Bsel[16] = {0,0,0,0,0,1,2,1,3,4,1,5,6,5,3,7};
__device__ const float d_Clm[16]  = {
    0.28209479177387814f, 0.4886025119029199f, 0.4886025119029199f,
    0.4886025119029199f,  1.0925484305920792f, 1.0925484305920792f,
    0.31539156525252005f, 1.0925484305920792f, 0.5462742152960396f,
    0.5900435899266435f,  2.890611442640554f,  0.4570457994644658f,
    0.3731763325901154f,  0.4570457994644658f, 1.445305721320277f,
    0.5900435899266435f };

__device__ __forceinline__ float ylm_eval(int asel, int bsel, float c_lm,
                                          float x, float y, float zz) {
    float x2 = x * x, y2 = y * y, z2 = zz * zz;
    float A = (asel == 0) ? 1.0f :
              (asel == 1) ? x    :
              (asel == 2) ? y    :
              (asel == 3) ? zz   : x * y;
    float B = (bsel == 0) ? 1.0f :
              (bsel == 1) ? zz   :
              (bsel == 2) ? fmaf(3.0f, z2, -1.0f) :
              (bsel == 3) ? (x2 - y2)             :
              (bsel == 4) ? fmaf(3.0f, x2, -y2)   :
              (bsel == 5) ? fmaf(5.0f, z2, -1.0f) :
              (bsel == 6) ? fmaf(5.0f, z2, -3.0f) :
                            fmaf(-3.0f, y2, x2);
    return c_lm * A * B;
}

__device__ __forceinline__ float4 make_rec(float d, float x, float y, float zz,
                                           int s) {
    unsigned db = (__float_as_uint(d) & ~3u) | (unsigned)s;  // <=2^-22 perturb
    float4 r; r.x = __uint_as_float(db); r.y = x; r.z = y; r.w = zz;
    return r;
}

// ---------------- prep: records in EDGE order (fully coalesced) ------------
__global__ void k_prep(const float* __restrict__ dist,
                       const float* __restrict__ dirs,
                       const int* __restrict__ zarr,
                       const int* __restrict__ idx_j,
                       float4* __restrict__ recs, int n_edges) {
    int e = blockIdx.x * blockDim.x + threadIdx.x;
    if (e >= n_edges) return;
    recs[e] = make_rec(dist[e], dirs[3*e], dirs[3*e+1], dirs[3*e+2],
                       zarr[idx_j[e]] & 3);
}

// ---------------- scatter ids into sub-buckets -----------------------------
template<int SUB, int CAPS>
__global__ void k_scat_ids(const int* __restrict__ idx_i,
                           int* __restrict__ cursors,
                           int* __restrict__ ids, int n_edges) {
    int e = blockIdx.x * blockDim.x + threadIdx.x;
    if (e >= n_edges) return;
    int a = idx_i[e];
    int s = e & (SUB - 1);
    int c = atomicAdd(&cursors[a * SUB + s], 1);
    if (c < CAPS) ids[((size_t)a * SUB + s) * CAPS + c] = e;
}

// ---------------- scatter full records into sub-buckets --------------------
template<int SUB, int CAPS>
__global__ void k_scat_rec(const float* __restrict__ dist,
                           const float* __restrict__ dirs,
                           const int* __restrict__ zarr,
                           const int* __restrict__ idx_i,
                           const int* __restrict__ idx_j,
                           int* __restrict__ cursors,
                           float4* __restrict__ recs, int n_edges) {
    int e = blockIdx.x * blockDim.x + threadIdx.x;
    if (e >= n_edges) return;
    float d = dist[e];
    float x = dirs[3*e], y = dirs[3*e+1], zz = dirs[3*e+2];
    int sp = zarr[idx_j[e]] & 3;
    int a = idx_i[e];
    int s = e & (SUB - 1);
    int c = atomicAdd(&cursors[a * SUB + s], 1);
    if (c < CAPS) recs[((size_t)a * SUB + s) * CAPS + c] = make_rec(d, x, y, zz, sp);
}

// ---------------- main per-atom kernel -------------------------------------
// MODE 0: ids indirection (recs in edge order); MODE 1: recs bucketed direct.
// 128 thr = 2 independent waves; wave handles 8 slots/iter, stride 16;
// 2-deep pipeline. Zero block barriers in the loop.
template<int SUB, int CAPS, int MODE>
__global__ __launch_bounds__(128) void k_main(
        const float4* __restrict__ recs, const int* __restrict__ ids,
        const float* __restrict__ W, const float* __restrict__ centers,
        const int* __restrict__ cursors, float* __restrict__ out) {
    const int atom = blockIdx.x;
    const int t = threadIdx.x;
    const int w = t >> 6, L = t & 63;
    const int lm = L & 15, g = L >> 4;
    const int l  = (lm >= 9) ? 3 : (lm >= 4) ? 2 : (lm >= 1) ? 1 : 0;
    const int r0 = l * 8 + g;
    const int row = L & 31, p = L >> 5;

    const float ck   = centers[lm];
    const float c_lm = d_Clm[lm];
    const int   asel = d_Asel[lm], bsel = d_Bsel[lm];
    const float4* wp = reinterpret_cast<const float4*>(W + (row << 4));
    const float4 w0 = wp[0], w1 = wp[1], w2 = wp[2], w3 = wp[3];

    __shared__ float ggfc[2][8][16];
    __shared__ float ylmS[2][8][16];
    __shared__ float rinS[2][8][32];
    __shared__ int   msS [2][8];
    __shared__ float red [2][8][64];

    // counts + register prefix over sub-buckets
    int pre[SUB + 1]; pre[0] = 0;
    #pragma unroll
    for (int s = 0; s < SUB; ++s) {
        int c = cursors[atom * SUB + s];
        c = (c < CAPS) ? c : CAPS;
        pre[s + 1] = pre[s] + c;
    }
    const int cnt = pre[SUB];
    const int* idsA = (MODE == 0) ? (ids + (size_t)atom * SUB * CAPS) : nullptr;
    const float4* rp = (MODE == 0) ? recs : (recs + (size_t)atom * SUB * CAPS);

    // slot q -> record index (within rp)
    auto getidx = [&](int q, bool v) -> int {
        int qq = v ? q : 0;
        int sb = 0, bs = 0;
        #pragma unroll
        for (int k = 1; k < SUB; ++k) {
            if (qq >= pre[k]) { sb = k; bs = pre[k]; }
        }
        int m = sb * CAPS + (qq - bs);
        return (MODE == 0) ? idsA[m] : m;
    };

    float a00=0.f,a01=0.f,a10=0.f,a11=0.f,a20=0.f,a21=0.f,a30=0.f,a31=0.f;

    if (cnt > 0) {
        int base = w * 8;
        int sA = base + g, sB = sA + 4;
        bool vA = sA < cnt, vB = sB < cnt;
        int iA = getidx(sA, vA), iB = getidx(sB, vB);
        int sA1 = sA + 16, sB1 = sB + 16;
        bool vA1 = sA1 < cnt, vB1 = sB1 < cnt;
        int iA1 = getidx(sA1, vA1), iB1 = getidx(sB1, vB1);
        float4 rA = rp[iA], rB = rp[iB];

        for (; base < cnt; base += 16) {
            float4 rAn = rp[iA1], rBn = rp[iB1];
            int sA2 = sA + 32, sB2 = sB + 32;
            bool vA2 = sA2 < cnt, vB2 = sB2 < cnt;
            int iA2 = getidx(sA2, vA2), iB2 = getidx(sB2, vB2);

            // ---- stage 1: g*fc + Ylm for slots g and g+4 ----
            {
                float d = rA.x, x = rA.y, y = rA.z, zz = rA.w;
                int spec = __float_as_uint(d) & 3;
                float tt = fminf(fmaxf((d - RIN_) * 2.0f, 0.0f), 1.0f);
                float fcv = 0.5f * (__cosf(PI_F * tt) + 1.0f);
                float dd = d - ck;
                float gv = __expf(-2.0f * dd * dd) * fcv;
                gv = vA ? gv : 0.0f;
                float yv = ylm_eval(asel, bsel, c_lm, x, y, zz);
                yv = vA ? yv : 0.0f;
                ggfc[w][g][lm] = gv; ylmS[w][g][lm] = yv;
                if (lm == 0) msS[w][g] = spec;
            }
            {
                float d = rB.x, x = rB.y, y = rB.z, zz = rB.w;
                int spec = __float_as_uint(d) & 3;
                float tt = fminf(fmaxf((d - RIN_) * 2.0f, 0.0f), 1.0f);
                float fcv = 0.5f * (__cosf(PI_F * tt) + 1.0f);
                float dd = d - ck;
                float gv = __expf(-2.0f * dd * dd) * fcv;
                gv = vB ? gv : 0.0f;
                float yv = ylm_eval(asel, bsel, c_lm, x, y, zz);
                yv = vB ? yv : 0.0f;
                ggfc[w][g + 4][lm] = gv; ylmS[w][g + 4][lm] = yv;
                if (lm == 0) msS[w][g + 4] = spec;
            }
            __builtin_amdgcn_wave_barrier();
            // ---- stage 2: RIln, 4 dot16 per lane ----
            #pragma unroll
            for (int q = 0; q < 4; ++q) {
                int e = p + 2 * q;
                const float4* ga = reinterpret_cast<const float4*>(&ggfc[w][e][0]);
                float4 A0 = ga[0], A1 = ga[1], A2 = ga[2], A3 = ga[3];
                float r = A0.x * w0.x;
                r = fmaf(A0.y, w0.y, r); r = fmaf(A0.z, w0.z, r); r = fmaf(A0.w, w0.w, r);
                r = fmaf(A1.x, w1.x, r); r = fmaf(A1.y, w1.y, r); r = fmaf(A1.z, w1.z, r); r = fmaf(A1.w, w1.w, r);
                r = fmaf(A2.x, w2.x, r); r = fmaf(A2.y, w2.y, r); r = fmaf(A2.z, w2.z, r); r = fmaf(A2.w, w2.w, r);
                r = fmaf(A3.x, w3.x, r); r = fmaf(A3.y, w3.y, r); r = fmaf(A3.z, w3.z, r); r = fmaf(A3.w, w3.w, r);
                rinS[w][e][row] = r;
            }
            __builtin_amdgcn_wave_barrier();
            // ---- stage 3: accumulate 8 slots ----
            #pragma unroll
            for (int e = 0; e < 8; ++e) {
                float ye = ylmS[w][e][lm];
                float va = rinS[w][e][r0];
                float vb = rinS[w][e][r0 + 4];
                int s = __builtin_amdgcn_readfirstlane(msS[w][e]);
                float v0 = va * ye, v1 = vb * ye;
                if (s == 0)      { a00 += v0; a01 += v1; }
                else if (s == 1) { a10 += v0; a11 += v1; }
                else if (s == 2) { a20 += v0; a21 += v1; }
                else             { a30 += v0; a31 += v1; }
            }
            __builtin_amdgcn_wave_barrier();

            rA = rAn; rB = rBn;
            vA = vA1; vB = vB1;
            sA = sA1; sB = sB1;
            sA1 = sA2; sB1 = sB2; vA1 = vA2; vB1 = vB2; iA1 = iA2; iB1 = iB2;
        }
    }

    red[w][0][L] = a00; red[w][1][L] = a01;
    red[w][2][L] = a10; red[w][3][L] = a11;
    red[w][4][L] = a20; red[w][5][L] = a21;
    red[w][6][L] = a30; red[w][7][L] = a31;
    __syncthreads();
    const int h = t >> 6, Ls = t & 63;
    float* ob = out + (size_t)atom * (NSPECC * NMAXC * LMC);
    #pragma unroll
    for (int s = 0; s < 4; ++s)
        ob[s * 128 + t] = red[0][s * 2 + h][Ls] + red[1][s * 2 + h][Ls];
}

// ---------------- last-resort fallback: direct atomics ---------------------
__device__ __forceinline__ float cutoff_fn(float d) {
    float tt = (d - RIN_) * 2.0f;
    tt = fminf(fmaxf(tt, 0.0f), 1.0f);
    float ramp = 0.5f * (cosf(PI_F * tt) + 1.0f);
    return (d < RCUT) ? ramp : 0.0f;
}

__global__ __launch_bounds__(128) void k_atomic(
        const float* __restrict__ distances, const float* __restrict__ dirs,
        const float* __restrict__ W, const float* __restrict__ centers,
        const int* __restrict__ zarr, const int* __restrict__ idx_i,
        const int* __restrict__ idx_j, float* __restrict__ out, int n_edges) {
    const int t = threadIdx.x;
    const int n = t >> 4, lm = t & 15;
    const int base = blockIdx.x * 8;

    __shared__ float4 gbuf[8][4];
    __shared__ float  ylm[8][16];
    __shared__ float  md[8], mfc[8], mx[8], my[8], mz[8];
    __shared__ int    ms[8], mi[8];

    const int l = (lm >= 9) ? 3 : (lm >= 4) ? 2 : (lm >= 1) ? 1 : 0;
    const float4* wp = reinterpret_cast<const float4*>(W + ((l * NMAXC + n) << 4));
    const float4 w0 = wp[0], w1 = wp[1], w2 = wp[2], w3 = wp[3];
    const float ck = centers[lm];

    if (t < 8) {
        int e = base + t;
        if (e < n_edges) {
            float d = distances[e];
            md[t] = d; mfc[t] = cutoff_fn(d);
            mx[t] = dirs[3 * e + 0];
            my[t] = dirs[3 * e + 1];
            mz[t] = dirs[3 * e + 2];
            ms[t] = zarr[idx_j[e]];
            mi[t] = idx_i[e];
        } else {
            md[t] = 1e9f; mfc[t] = 0.f;
            mx[t] = 0.f; my[t] = 0.f; mz[t] = 0.f; ms[t] = 0; mi[t] = 0;
        }
    }
    __syncthreads();
    {
        int e = t >> 4;
        float dd = md[e] - ck;
        reinterpret_cast<float*>(&gbuf[e][0])[lm] = __expf(-2.0f * dd * dd) * mfc[e];
    }
    {
        int e2 = t & 7, lm2 = t >> 3;
        ylm[e2][lm2] = ylm_eval(d_Asel[lm2], d_Bsel[lm2], d_Clm[lm2],
                                mx[e2], my[e2], mz[e2]);
    }
    __syncthreads();
    #pragma unroll
    for (int e = 0; e < 8; ++e) {
        float4 a0 = gbuf[e][0], a1 = gbuf[e][1], a2 = gbuf[e][2], a3 = gbuf[e][3];
        float r;
        r = a0.x * w0.x;
        r = fmaf(a0.y, w0.y, r); r = fmaf(a0.z, w0.z, r); r = fmaf(a0.w, w0.w, r);
        r = fmaf(a1.x, w1.x, r); r = fmaf(a1.y, w1.y, r); r = fmaf(a1.z, w1.z, r); r = fmaf(a1.w, w1.w, r);
        r = fmaf(a2.x, w2.x, r); r = fmaf(a2.y, w2.y, r); r = fmaf(a2.z, w2.z, r); r = fmaf(a2.w, w2.w, r);
        r = fmaf(a3.x, w3.x, r); r = fmaf(a3.y, w3.y, r); r = fmaf(a3.z, w3.z, r); r = fmaf(a3.w, w3.w, r);
        float v = r * ylm[e][lm];
        int target = (mi[e] * NSPECC + ms[e]) * (NMAXC * LMC) + t;
        unsafeAtomicAdd(&out[target], v);
    }
}

// ---------------------------------------------------------------------------
extern "C" void kernel_launch(void* const* d_in, const int* in_sizes, int n_in,
                              void* d_out, int out_size, void* d_ws, size_t ws_size,
                              hipStream_t stream) {
    const float* distances = (const float*)d_in[0];
    const float* dirs      = (const float*)d_in[1];
    const float* W         = (const float*)d_in[2];
    const float* centers   = (const float*)d_in[3];
    const int*   zarr      = (const int*)d_in[4];
    const int*   idx_i     = (const int*)d_in[5];
    const int*   idx_j     = (const int*)d_in[6];
    float*       out       = (float*)d_out;

    const int n_edges = in_sizes[0];
    const int n_atoms = in_sizes[4];
    const int eb = (n_edges + 255) / 256;

    const size_t recsE_b = (size_t)n_edges * sizeof(float4);                 // 12.8MB

    // Tier A: direct record sub-buckets (SUB=8, CAPS=32)
    const size_t cursA_b = (size_t)n_atoms * 8 * sizeof(int);                // 0.64MB
    const size_t recsA_b = (size_t)n_atoms * 8 * 32 * sizeof(float4);        // 81.9MB
    const size_t need_a  = cursA_b + recsA_b + 64;
    // Tier B: id sub-buckets (SUB=8, CAPS=32) + edge-order records
    const size_t idsB_b  = (size_t)n_atoms * 8 * 32 * sizeof(int);           // 20.5MB
    const size_t need_b  = cursA_b + idsB_b + recsE_b + 64;                  // ~34MB
    // Tier C: flat (SUB=1, CAPS=128) + edge-order records  (R6 replica)
    const size_t cursC_b = (size_t)n_atoms * sizeof(int);
    const size_t idsC_b  = (size_t)n_atoms * 128 * sizeof(int);              // 10.24MB
    const size_t need_c  = cursC_b + idsC_b + recsE_b + 64;                  // ~23.2MB

    if (ws_size >= need_a) {
        int*    cursors = (int*)d_ws;
        float4* recsB   = (float4*)((char*)d_ws + cursA_b);
        hipMemsetAsync(cursors, 0, cursA_b, stream);
        k_scat_rec<8,32><<<eb, 256, 0, stream>>>(distances, dirs, zarr, idx_i,
                                                 idx_j, cursors, recsB, n_edges);
        k_main<8,32,1><<<n_atoms, 128, 0, stream>>>(recsB, nullptr, W, centers,
                                                    cursors, out);
    } else if (ws_size >= need_b) {
        int*    cursors = (int*)d_ws;
        int*    ids     = (int*)((char*)d_ws + cursA_b);
        float4* recsE   = (float4*)((char*)d_ws + cursA_b + idsB_b);
        hipMemsetAsync(cursors, 0, cursA_b, stream);
        k_prep<<<eb, 256, 0, stream>>>(distances, dirs, zarr, idx_j, recsE, n_edges);
        k_scat_ids<8,32><<<eb, 256, 0, stream>>>(idx_i, cursors, ids, n_edges);
        k_main<8,32,0><<<n_atoms, 128, 0, stream>>>(recsE, ids, W, centers,
                                                    cursors, out);
    } else if (ws_size >= need_c) {
        int*    cursors = (int*)d_ws;
        int*    ids     = (int*)((char*)d_ws + cursC_b);
        float4* recsE   = (float4*)((char*)d_ws + cursC_b + idsC_b);
        hipMemsetAsync(cursors, 0, cursC_b, stream);
        k_prep<<<eb, 256, 0, stream>>>(distances, dirs, zarr, idx_j, recsE, n_edges);
        k_scat_ids<1,128><<<eb, 256, 0, stream>>>(idx_i, cursors, ids, n_edges);
        k_main<1,128,0><<<n_atoms, 128, 0, stream>>>(recsE, ids, W, centers,
                                                     cursors, out);
    } else {
        hipMemsetAsync(out, 0, (size_t)out_size * sizeof(float), stream);
        k_atomic<<<(n_edges + 7) / 8, 128, 0, stream>>>(distances, dirs, W, centers,
                                                        zarr, idx_i, idx_j, out, n_edges);
    }
}

// Round 8
// 199.254 us; speedup vs baseline: 1.0626x; 1.0305x over previous
//
#include <hip/hip_runtime.h>

// ---------------------------------------------------------------------------
// SphericalExpansion. R8 design.
//  Attribution insight (R3-R7): ~100us of dur_us is FIXED harness overhead
//  (restore/poison dispatches; aux kernels never appear in top-5 => each
//  <78us; sum of our kernels + 100 matches every round). Scatter was never
//  the bottleneck (~15-20us). Only real lever: k_main (84us, VALU-bound 78%).
//  Restructure:
//   OUT[s,n,lm] = sum_k W[l(lm),n,k] * T[s,lm,k],
//   T[s,lm,k]   = sum_e Y[e,lm] * g_k(d_e) * fc_e      (rank-1 per edge)
//  -> inner loop: 256 MAC/edge (4 wave-insts), no W, no rin/stage3;
//     W-contraction once per atom in epilogue (~2.5 slots/edge amortized).
//  Plus: Ylm = (L1.v)(L2.v)(L3.v) linear-factor form (9 fma, no cndmask
//  chains); flat contiguous record buckets (no ids, no getidx); 1 wave/block
//  (zero block barriers); 1-deep prefetch.
// ---------------------------------------------------------------------------

#define NMAXC   8
#define LMC     16
#define NSPECC  4
#define RCUT    5.0f
#define RIN_    4.5f
#define PI_F    3.14159265358979323846f
#define CAP     128   // Poisson(40): P(>128) ~ 1e-28

// Ylm = (c1.v)*(c2.v)*(c3.v), v=(x,y,z,1); overall constant folded into c1.
// sqrt3=1.7320508075688772, sqrt5=2.23606797749979
__device__ __align__(16) const float YC[16][12] = {
  {0,0,0,0.28209479177387814f,                      0,0,0,1,                       0,0,0,1},
  {0,0.4886025119029199f,0,0,                       0,0,0,1,                       0,0,0,1},
  {0,0,0.4886025119029199f,0,                       0,0,0,1,                       0,0,0,1},
  {0.4886025119029199f,0,0,0,                       0,0,0,1,                       0,0,0,1},
  {1.0925484305920792f,0,0,0,                       0,1,0,0,                       0,0,0,1},
  {0,1.0925484305920792f,0,0,                       0,0,1,0,                       0,0,0,1},
  {0,0,0.5462742152960396f,0.31539156525252005f,    0,0,1.7320508075688772f,-1,    0,0,0,1},
  {1.0925484305920792f,0,0,0,                       0,0,1,0,                       0,0,0,1},
  {0.5462742152960396f,0.5462742152960396f,0,0,     1,-1,0,0,                      0,0,0,1},
  {0,0.5900435899266435f,0,0,                       1.7320508075688772f,1,0,0,     1.7320508075688772f,-1,0,0},
  {2.890611442640554f,0,0,0,                        0,1,0,0,                       0,0,1,0},
  {0,0.4570457994644658f,0,0,                       0,0,2.23606797749979f,1,       0,0,2.23606797749979f,-1},
  {0,0,0.3731763325901154f,0,                       0,0,2.23606797749979f,1.7320508075688772f, 0,0,2.23606797749979f,-1.7320508075688772f},
  {0.4570457994644658f,0,0,0,                       0,0,2.23606797749979f,1,       0,0,2.23606797749979f,-1},
  {0,0,1.445305721320277f,0,                        1,1,0,0,                       1,-1,0,0},
  {0.5900435899266435f,0,0,0,                       1,1.7320508075688772f,0,0,     1,-1.7320508075688772f,0,0}
};

// ---------------- scatter full records into flat per-atom buckets ----------
__global__ void k_scat(const float* __restrict__ dist,
                       const float* __restrict__ dirs,
                       const int* __restrict__ zarr,
                       const int* __restrict__ idx_i,
                       const int* __restrict__ idx_j,
                       int* __restrict__ cursors,
                       float4* __restrict__ recs, int n_edges) {
    int e = blockIdx.x * blockDim.x + threadIdx.x;
    if (e >= n_edges) return;
    float d = dist[e];
    float x = dirs[3*e], y = dirs[3*e+1], z = dirs[3*e+2];
    int sp = zarr[idx_j[e]] & 3;                              // z: 80KB, L2-hit
    int a = idx_i[e];
    int c = atomicAdd(&cursors[a], 1);
    if (c < CAP) {
        unsigned db = (__float_as_uint(d) & ~3u) | (unsigned)sp; // <=2^-22 perturb
        float4 r; r.x = __uint_as_float(db); r.y = x; r.z = y; r.w = z;
        recs[(size_t)a * CAP + c] = r;
    }
}

// ---------------- main: 1 wave per atom, T-accumulation --------------------
#define ACC4(S) \
    Ts[S][0] = fmaf(yl, g4.x, Ts[S][0]); Ts[S][1] = fmaf(yl, g4.y, Ts[S][1]); \
    Ts[S][2] = fmaf(yl, g4.z, Ts[S][2]); Ts[S][3] = fmaf(yl, g4.w, Ts[S][3]);

__global__ __launch_bounds__(64) void k_mainT(
        const float4* __restrict__ recs, const float* __restrict__ W,
        const float* __restrict__ centers, const int* __restrict__ cursors,
        float* __restrict__ out) {
    const int atom = blockIdx.x;
    const int L = threadIdx.x;
    const int lm = L & 15;      // stage1: basis k index AND Ylm index; stageT: lm
    const int eL = L >> 4;      // stage1: edge group 0..3; stageT: k-quad; epi: n0
    const float ck = centers[lm];
    const float4* yc = reinterpret_cast<const float4*>(&YC[lm][0]);
    const float4 c1 = yc[0], c2 = yc[1], c3 = yc[2];

    __shared__ float gS[8][16];                 // g_k * fc   [edge][k]
    __shared__ float yS[8][16];                 // Ylm        [edge][lm]
    __shared__ int   mS[8];                     // species
    __shared__ __align__(16) float Tl[4][16][20];  // T dump (+pad 16->20)

    int cnt = cursors[atom]; if (cnt > CAP) cnt = CAP;
    const float4* rp = recs + (size_t)atom * CAP;

    float Ts[4][4] = {};                        // T[s][j], k = eL*4 + j

    if (cnt > 0) {
        int sA = eL, sB = eL + 4;
        bool vA = sA < cnt, vB = sB < cnt;
        float4 rA = rp[vA ? sA : 0];
        float4 rB = rp[vB ? sB : 0];

        for (int base = 0; base < cnt; base += 8) {
            // 1-deep prefetch (contiguous, independent addresses)
            int nA = base + 8 + eL, nB = base + 12 + eL;
            bool vAn = nA < cnt, vBn = nB < cnt;
            float4 rAn = rp[vAn ? nA : 0];
            float4 rBn = rp[vBn ? nB : 0];

            // ---- stage 1: g*fc + Ylm for edges (base+eL) and (base+4+eL) ----
            {
                float d = rA.x, x = rA.y, y = rA.z, z = rA.w;
                int sp = __float_as_uint(d) & 3;
                float tt = fminf(fmaxf((d - RIN_) * 2.0f, 0.0f), 1.0f);
                float fcv = 0.5f * (__cosf(PI_F * tt) + 1.0f);
                float dd = d - ck;
                float gv = __expf(-2.0f * dd * dd) * fcv;
                gv = vA ? gv : 0.0f;            // invalid slot -> zero contribution
                float f1 = fmaf(c1.x, x, fmaf(c1.y, y, fmaf(c1.z, z, c1.w)));
                float f2 = fmaf(c2.x, x, fmaf(c2.y, y, fmaf(c2.z, z, c2.w)));
                float f3 = fmaf(c3.x, x, fmaf(c3.y, y, fmaf(c3.z, z, c3.w)));
                gS[eL][lm] = gv;
                yS[eL][lm] = f1 * f2 * f3;
                if (lm == 0) mS[eL] = sp;
            }
            {
                float d = rB.x, x = rB.y, y = rB.z, z = rB.w;
                int sp = __float_as_uint(d) & 3;
                float tt = fminf(fmaxf((d - RIN_) * 2.0f, 0.0f), 1.0f);
                float fcv = 0.5f * (__cosf(PI_F * tt) + 1.0f);
                float dd = d - ck;
                float gv = __expf(-2.0f * dd * dd) * fcv;
                gv = vB ? gv : 0.0f;
                float f1 = fmaf(c1.x, x, fmaf(c1.y, y, fmaf(c1.z, z, c1.w)));
                float f2 = fmaf(c2.x, x, fmaf(c2.y, y, fmaf(c2.z, z, c2.w)));
                float f3 = fmaf(c3.x, x, fmaf(c3.y, y, fmaf(c3.z, z, c3.w)));
                gS[eL + 4][lm] = gv;
                yS[eL + 4][lm] = f1 * f2 * f3;
                if (lm == 0) mS[eL + 4] = sp;
            }
            __builtin_amdgcn_wave_barrier();    // in-order DS pipe, same wave
            // ---- stage T: rank-1 accumulate, 8 edges ----
            #pragma unroll
            for (int e = 0; e < 8; ++e) {
                float yl = yS[e][lm];                                   // bcast
                float4 g4 = *reinterpret_cast<const float4*>(&gS[e][eL << 2]);
                int sp = __builtin_amdgcn_readfirstlane(mS[e]);         // uniform
                if (sp == 0)      { ACC4(0) }
                else if (sp == 1) { ACC4(1) }
                else if (sp == 2) { ACC4(2) }
                else              { ACC4(3) }
            }
            __builtin_amdgcn_wave_barrier();

            rA = rAn; rB = rBn; vA = vAn; vB = vBn;
        }
    }

    // ---- epilogue: dump T, contract with W once per atom ----
    #pragma unroll
    for (int s = 0; s < 4; ++s) {
        float4 v; v.x = Ts[s][0]; v.y = Ts[s][1]; v.z = Ts[s][2]; v.w = Ts[s][3];
        *reinterpret_cast<float4*>(&Tl[s][lm][eL << 2]) = v;
    }
    __builtin_amdgcn_wave_barrier();

    const int l = (lm >= 9) ? 3 : (lm >= 4) ? 2 : (lm >= 1) ? 1 : 0;
    const float4* wA = reinterpret_cast<const float4*>(W + (l * 8 + eL) * 16);
    const float4* wB = reinterpret_cast<const float4*>(W + (l * 8 + eL + 4) * 16);
    const float4 a0 = wA[0], a1 = wA[1], a2 = wA[2], a3 = wA[3];
    const float4 b0 = wB[0], b1 = wB[1], b2 = wB[2], b3 = wB[3];
    float* ob = out + (size_t)atom * (NSPECC * NMAXC * LMC);
    #pragma unroll
    for (int s = 0; s < 4; ++s) {
        float4 t0 = *reinterpret_cast<const float4*>(&Tl[s][lm][0]);
        float4 t1 = *reinterpret_cast<const float4*>(&Tl[s][lm][4]);
        float4 t2 = *reinterpret_cast<const float4*>(&Tl[s][lm][8]);
        float4 t3 = *reinterpret_cast<const float4*>(&Tl[s][lm][12]);
        float va = t0.x * a0.x;
        va = fmaf(t0.y, a0.y, va); va = fmaf(t0.z, a0.z, va); va = fmaf(t0.w, a0.w, va);
        va = fmaf(t1.x, a1.x, va); va = fmaf(t1.y, a1.y, va); va = fmaf(t1.z, a1.z, va); va = fmaf(t1.w, a1.w, va);
        va = fmaf(t2.x, a2.x, va); va = fmaf(t2.y, a2.y, va); va = fmaf(t2.z, a2.z, va); va = fmaf(t2.w, a2.w, va);
        va = fmaf(t3.x, a3.x, va); va = fmaf(t3.y, a3.y, va); va = fmaf(t3.z, a3.z, va); va = fmaf(t3.w, a3.w, va);
        float vb = t0.x * b0.x;
        vb = fmaf(t0.y, b0.y, vb); vb = fmaf(t0.z, b0.z, vb); vb = fmaf(t0.w, b0.w, vb);
        vb = fmaf(t1.x, b1.x, vb); vb = fmaf(t1.y, b1.y, vb); vb = fmaf(t1.z, b1.z, vb); vb = fmaf(t1.w, b1.w, vb);
        vb = fmaf(t2.x, b2.x, vb); vb = fmaf(t2.y, b2.y, vb); vb = fmaf(t2.z, b2.z, vb); vb = fmaf(t2.w, b2.w, vb);
        vb = fmaf(t3.x, b3.x, vb); vb = fmaf(t3.y, b3.y, vb); vb = fmaf(t3.z, b3.z, vb); vb = fmaf(t3.w, b3.w, vb);
        ob[s * 128 + L]      = va;   // n = eL     (L = eL*16+lm)
        ob[s * 128 + 64 + L] = vb;   // n = eL + 4
    }
}

// ---------------- last-resort fallback: direct atomics ---------------------
__global__ __launch_bounds__(128) void k_atomic(
        const float* __restrict__ distances, const float* __restrict__ dirs,
        const float* __restrict__ W, const float* __restrict__ centers,
        const int* __restrict__ zarr, const int* __restrict__ idx_i,
        const int* __restrict__ idx_j, float* __restrict__ out, int n_edges) {
    const int t = threadIdx.x;
    const int n = t >> 4, lm = t & 15;
    const int base = blockIdx.x * 8;

    __shared__ float4 gbuf[8][4];
    __shared__ float  ylm[8][16];
    __shared__ float  md[8], mfc[8], mx[8], my[8], mz[8];
    __shared__ int    ms[8], mi[8];

    const int l = (lm >= 9) ? 3 : (lm >= 4) ? 2 : (lm >= 1) ? 1 : 0;
    const float4* wp = reinterpret_cast<const float4*>(W + ((l * NMAXC + n) << 4));
    const float4 w0 = wp[0], w1 = wp[1], w2 = wp[2], w3 = wp[3];
    const float ck = centers[lm];

    if (t < 8) {
        int e = base + t;
        if (e < n_edges) {
            float d = distances[e];
            float tt = fminf(fmaxf((d - RIN_) * 2.0f, 0.0f), 1.0f);
            md[t] = d; mfc[t] = 0.5f * (cosf(PI_F * tt) + 1.0f) * (d < RCUT ? 1.f : 0.f);
            mx[t] = dirs[3 * e + 0];
            my[t] = dirs[3 * e + 1];
            mz[t] = dirs[3 * e + 2];
            ms[t] = zarr[idx_j[e]];
            mi[t] = idx_i[e];
        } else {
            md[t] = 1e9f; mfc[t] = 0.f;
            mx[t] = 0.f; my[t] = 0.f; mz[t] = 0.f; ms[t] = 0; mi[t] = 0;
        }
    }
    __syncthreads();
    {
        int e = t >> 4;
        float dd = md[e] - ck;
        reinterpret_cast<float*>(&gbuf[e][0])[lm] = __expf(-2.0f * dd * dd) * mfc[e];
    }
    {
        int e2 = t & 7, lm2 = t >> 3;
        const float* yc = &YC[lm2][0];
        float x = mx[e2], y = my[e2], z = mz[e2];
        float f1 = fmaf(yc[0], x, fmaf(yc[1], y, fmaf(yc[2], z, yc[3])));
        float f2 = fmaf(yc[4], x, fmaf(yc[5], y, fmaf(yc[6], z, yc[7])));
        float f3 = fmaf(yc[8], x, fmaf(yc[9], y, fmaf(yc[10], z, yc[11])));
        ylm[e2][lm2] = f1 * f2 * f3;
    }
    __syncthreads();
    #pragma unroll
    for (int e = 0; e < 8; ++e) {
        float4 a0 = gbuf[e][0], a1 = gbuf[e][1], a2 = gbuf[e][2], a3 = gbuf[e][3];
        float r;
        r = a0.x * w0.x;
        r = fmaf(a0.y, w0.y, r); r = fmaf(a0.z, w0.z, r); r = fmaf(a0.w, w0.w, r);
        r = fmaf(a1.x, w1.x, r); r = fmaf(a1.y, w1.y, r); r = fmaf(a1.z, w1.z, r); r = fmaf(a1.w, w1.w, r);
        r = fmaf(a2.x, w2.x, r); r = fmaf(a2.y, w2.y, r); r = fmaf(a2.z, w2.z, r); r = fmaf(a2.w, w2.w, r);
        r = fmaf(a3.x, w3.x, r); r = fmaf(a3.y, w3.y, r); r = fmaf(a3.z, w3.z, r); r = fmaf(a3.w, w3.w, r);
        float v = r * ylm[e][lm];
        int target = (mi[e] * NSPECC + ms[e]) * (NMAXC * LMC) + t;
        unsafeAtomicAdd(&out[target], v);
    }
}

// ---------------------------------------------------------------------------
extern "C" void kernel_launch(void* const* d_in, const int* in_sizes, int n_in,
                              void* d_out, int out_size, void* d_ws, size_t ws_size,
                              hipStream_t stream) {
    const float* distances = (const float*)d_in[0];
    const float* dirs      = (const float*)d_in[1];
    const float* W         = (const float*)d_in[2];
    const float* centers   = (const float*)d_in[3];
    const int*   zarr      = (const int*)d_in[4];
    const int*   idx_i     = (const int*)d_in[5];
    const int*   idx_j     = (const int*)d_in[6];
    float*       out       = (float*)d_out;

    const int n_edges = in_sizes[0];
    const int n_atoms = in_sizes[4];
    const int eb = (n_edges + 255) / 256;

    const size_t curs_b = (size_t)n_atoms * sizeof(int);                 // 80KB
    const size_t recs_b = (size_t)n_atoms * CAP * sizeof(float4);        // 41MB
    const size_t need   = curs_b + recs_b + 64;

    if (ws_size >= need) {
        int*    cursors = (int*)d_ws;
        float4* recs    = (float4*)((char*)d_ws + curs_b);
        hipMemsetAsync(cursors, 0, curs_b, stream);
        k_scat<<<eb, 256, 0, stream>>>(distances, dirs, zarr, idx_i, idx_j,
                                       cursors, recs, n_edges);
        k_mainT<<<n_atoms, 64, 0, stream>>>(recs, W, centers, cursors, out);
    } else {
        hipMemsetAsync(out, 0, (size_t)out_size * sizeof(float), stream);
        k_atomic<<<(n_edges + 7) / 8, 128, 0, stream>>>(distances, dirs, W, centers,
                                                        zarr, idx_i, idx_j, out, n_edges);
    }
}

// Round 11
// 196.025 us; speedup vs baseline: 1.0801x; 1.0165x over previous
//
#include <hip/hip_runtime.h>

// ---------------------------------------------------------------------------
// SphericalExpansion. R9 design (resubmit R11 — two GPU timeouts, unbenched).
//  R8 measured: k_mainT 71.6us, VALUBusy 65%, Occupancy 33.8% (64-thr blocks
//  hit the ~16 workgroup-slots/CU limit -> ~11-16 waves/CU; latency-bound).
//  Fix: 4 independent atoms per 256-thr block (4 waves, zero cross-wave
//  coupling, all barriers stay wave-level) -> 4x waves per block slot.
//  LDS: union the Tl epilogue buffer with loop gS/yS (loop retired before
//  epilogue, same-wave order via wave_barrier) -> ~20.8KB/block -> 7 blocks
//  -> ~28 waves/CU (87%).
//  Math (from R8): T[s,lm,k] = sum_e Y[e,lm]*g_k(d_e)*fc_e (rank-1/edge,
//  4 wave-insts/edge), OUT = W-contraction once per atom in epilogue.
// ---------------------------------------------------------------------------

#define NMAXC   8
#define LMC     16
#define NSPECC  4
#define RCUT    5.0f
#define RIN_    4.5f
#define PI_F    3.14159265358979323846f
#define CAP     128   // Poisson(40): P(>128) ~ 1e-28
#define WPB     4     // waves (atoms) per block

// Ylm = (c1.v)*(c2.v)*(c3.v), v=(x,y,z,1); overall constant folded into c1.
__device__ __align__(16) const float YC[16][12] = {
  {0,0,0,0.28209479177387814f,                      0,0,0,1,                       0,0,0,1},
  {0,0.4886025119029199f,0,0,                       0,0,0,1,                       0,0,0,1},
  {0,0,0.4886025119029199f,0,                       0,0,0,1,                       0,0,0,1},
  {0.4886025119029199f,0,0,0,                       0,0,0,1,                       0,0,0,1},
  {1.0925484305920792f,0,0,0,                       0,1,0,0,                       0,0,0,1},
  {0,1.0925484305920792f,0,0,                       0,0,1,0,                       0,0,0,1},
  {0,0,0.5462742152960396f,0.31539156525252005f,    0,0,1.7320508075688772f,-1,    0,0,0,1},
  {1.0925484305920792f,0,0,0,                       0,0,1,0,                       0,0,0,1},
  {0.5462742152960396f,0.5462742152960396f,0,0,     1,-1,0,0,                      0,0,0,1},
  {0,0.5900435899266435f,0,0,                       1.7320508075688772f,1,0,0,     1.7320508075688772f,-1,0,0},
  {2.890611442640554f,0,0,0,                        0,1,0,0,                       0,0,1,0},
  {0,0.4570457994644658f,0,0,                       0,0,2.23606797749979f,1,       0,0,2.23606797749979f,-1},
  {0,0,0.3731763325901154f,0,                       0,0,2.23606797749979f,1.7320508075688772f, 0,0,2.23606797749979f,-1.7320508075688772f},
  {0.4570457994644658f,0,0,0,                       0,0,2.23606797749979f,1,       0,0,2.23606797749979f,-1},
  {0,0,1.445305721320277f,0,                        1,1,0,0,                       1,-1,0,0},
  {0.5900435899266435f,0,0,0,                       1,1.7320508075688772f,0,0,     1,-1.7320508075688772f,0,0}
};

// ---------------- scatter full records into flat per-atom buckets ----------
__global__ void k_scat(const float* __restrict__ dist,
                       const float* __restrict__ dirs,
                       const int* __restrict__ zarr,
                       const int* __restrict__ idx_i,
                       const int* __restrict__ idx_j,
                       int* __restrict__ cursors,
                       float4* __restrict__ recs, int n_edges) {
    int e = blockIdx.x * blockDim.x + threadIdx.x;
    if (e >= n_edges) return;
    float d = dist[e];
    float x = dirs[3*e], y = dirs[3*e+1], z = dirs[3*e+2];
    int sp = zarr[idx_j[e]] & 3;                              // z: 80KB, L2-hit
    int a = idx_i[e];
    int c = atomicAdd(&cursors[a], 1);
    if (c < CAP) {
        unsigned db = (__float_as_uint(d) & ~3u) | (unsigned)sp; // <=2^-22 perturb
        float4 r; r.x = __uint_as_float(db); r.y = x; r.z = y; r.w = z;
        recs[(size_t)a * CAP + c] = r;
    }
}

// ---------------- main: 4 independent waves per block, T-accumulation ------
#define ACC4(S) \
    Ts[S][0] = fmaf(yl, g4.x, Ts[S][0]); Ts[S][1] = fmaf(yl, g4.y, Ts[S][1]); \
    Ts[S][2] = fmaf(yl, g4.z, Ts[S][2]); Ts[S][3] = fmaf(yl, g4.w, Ts[S][3]);

// per-wave LDS: buf[1280] floats, dual-use:
//   loop:     gS = buf[0..127]  (g[edge][k]),  yS = buf[128..255] (Y[edge][lm])
//   epilogue: Tl = buf[0..1279] ([4 species][16 lm][20 (16k+pad)])
__global__ __launch_bounds__(256) void k_mainT(
        const float4* __restrict__ recs, const float* __restrict__ W,
        const float* __restrict__ centers, const int* __restrict__ cursors,
        float* __restrict__ out, int n_atoms) {
    const int w = threadIdx.x >> 6;
    const int atom = blockIdx.x * WPB + w;
    const int L = threadIdx.x & 63;
    const int lm = L & 15;      // stage1: basis k AND Ylm index; stageT/epi: lm
    const int eL = L >> 4;      // stage1: edge group; stageT: k-quad; epi: n0

    __shared__ __align__(16) float buf[WPB][1280];
    __shared__ int mS[WPB][8];

    if (atom >= n_atoms) return;   // safe: only wave-level barriers below

    float* gS = &buf[w][0];        // [8][16]
    float* yS = &buf[w][128];      // [8][16]
    float* Tl = &buf[w][0];        // [4][16][20] (epilogue, after loop retires)

    const float ck = centers[lm];
    const float4* yc = reinterpret_cast<const float4*>(&YC[lm][0]);
    const float4 c1 = yc[0], c2 = yc[1], c3 = yc[2];

    int cnt = cursors[atom]; if (cnt > CAP) cnt = CAP;
    const float4* rp = recs + (size_t)atom * CAP;

    float Ts[4][4] = {};           // T[s][j], k = eL*4 + j

    if (cnt > 0) {
        int sA = eL, sB = eL + 4;
        bool vA = sA < cnt, vB = sB < cnt;
        float4 rA = rp[vA ? sA : 0];
        float4 rB = rp[vB ? sB : 0];

        for (int base = 0; base < cnt; base += 8) {
            // 1-deep prefetch (contiguous, independent addresses)
            int nA = base + 8 + eL, nB = base + 12 + eL;
            bool vAn = nA < cnt, vBn = nB < cnt;
            float4 rAn = rp[vAn ? nA : 0];
            float4 rBn = rp[vBn ? nB : 0];

            // ---- stage 1: g*fc + Ylm for edges (base+eL), (base+4+eL) ----
            {
                float d = rA.x, x = rA.y, y = rA.z, z = rA.w;
                int sp = __float_as_uint(d) & 3;
                float tt = fminf(fmaxf((d - RIN_) * 2.0f, 0.0f), 1.0f);
                float fcv = 0.5f * (__cosf(PI_F * tt) + 1.0f);
                float dd = d - ck;
                float gv = __expf(-2.0f * dd * dd) * fcv;
                gv = vA ? gv : 0.0f;           // invalid slot -> zero contribution
                float f1 = fmaf(c1.x, x, fmaf(c1.y, y, fmaf(c1.z, z, c1.w)));
                float f2 = fmaf(c2.x, x, fmaf(c2.y, y, fmaf(c2.z, z, c2.w)));
                float f3 = fmaf(c3.x, x, fmaf(c3.y, y, fmaf(c3.z, z, c3.w)));
                gS[eL * 16 + lm] = gv;
                yS[eL * 16 + lm] = f1 * f2 * f3;
                if (lm == 0) mS[w][eL] = sp;
            }
            {
                float d = rB.x, x = rB.y, y = rB.z, z = rB.w;
                int sp = __float_as_uint(d) & 3;
                float tt = fminf(fmaxf((d - RIN_) * 2.0f, 0.0f), 1.0f);
                float fcv = 0.5f * (__cosf(PI_F * tt) + 1.0f);
                float dd = d - ck;
                float gv = __expf(-2.0f * dd * dd) * fcv;
                gv = vB ? gv : 0.0f;
                float f1 = fmaf(c1.x, x, fmaf(c1.y, y, fmaf(c1.z, z, c1.w)));
                float f2 = fmaf(c2.x, x, fmaf(c2.y, y, fmaf(c2.z, z, c2.w)));
                float f3 = fmaf(c3.x, x, fmaf(c3.y, y, fmaf(c3.z, z, c3.w)));
                gS[(eL + 4) * 16 + lm] = gv;
                yS[(eL + 4) * 16 + lm] = f1 * f2 * f3;
                if (lm == 0) mS[w][eL + 4] = sp;
            }
            __builtin_amdgcn_wave_barrier();   // in-order DS pipe, same wave
            // ---- stage T: rank-1 accumulate, 8 edges ----
            #pragma unroll
            for (int e = 0; e < 8; ++e) {
                float yl = yS[e * 16 + lm];                               // bcast
                float4 g4 = *reinterpret_cast<const float4*>(&gS[e * 16 + (eL << 2)]);
                int sp = __builtin_amdgcn_readfirstlane(mS[w][e]);        // uniform
                if (sp == 0)      { ACC4(0) }
                else if (sp == 1) { ACC4(1) }
                else if (sp == 2) { ACC4(2) }
                else              { ACC4(3) }
            }
            __builtin_amdgcn_wave_barrier();

            rA = rAn; rB = rBn; vA = vAn; vB = vBn;
        }
    }

    // ---- epilogue: dump T into (reused) LDS, contract with W ----
    __builtin_amdgcn_wave_barrier();           // loop's gS/yS reads retired
    #pragma unroll
    for (int s = 0; s < 4; ++s) {
        float4 v; v.x = Ts[s][0]; v.y = Ts[s][1]; v.z = Ts[s][2]; v.w = Ts[s][3];
        *reinterpret_cast<float4*>(&Tl[s * 320 + lm * 20 + (eL << 2)]) = v;
    }
    __builtin_amdgcn_wave_barrier();

    const int l = (lm >= 9) ? 3 : (lm >= 4) ? 2 : (lm >= 1) ? 1 : 0;
    const float4* wA = reinterpret_cast<const float4*>(W + (l * 8 + eL) * 16);
    const float4* wB = reinterpret_cast<const float4*>(W + (l * 8 + eL + 4) * 16);
    const float4 a0 = wA[0], a1 = wA[1], a2 = wA[2], a3 = wA[3];
    const float4 b0 = wB[0], b1 = wB[1], b2 = wB[2], b3 = wB[3];
    float* ob = out + (size_t)atom * (NSPECC * NMAXC * LMC);
    #pragma unroll
    for (int s = 0; s < 4; ++s) {
        const float* tb = &Tl[s * 320 + lm * 20];
        float4 t0 = *reinterpret_cast<const float4*>(tb);
        float4 t1 = *reinterpret_cast<const float4*>(tb + 4);
        float4 t2 = *reinterpret_cast<const float4*>(tb + 8);
        float4 t3 = *reinterpret_cast<const float4*>(tb + 12);
        float va = t0.x * a0.x;
        va = fmaf(t0.y, a0.y, va); va = fmaf(t0.z, a0.z, va); va = fmaf(t0.w, a0.w, va);
        va = fmaf(t1.x, a1.x, va); va = fmaf(t1.y, a1.y, va); va = fmaf(t1.z, a1.z, va); va = fmaf(t1.w, a1.w, va);
        va = fmaf(t2.x, a2.x, va); va = fmaf(t2.y, a2.y, va); va = fmaf(t2.z, a2.z, va); va = fmaf(t2.w, a2.w, va);
        va = fmaf(t3.x, a3.x, va); va = fmaf(t3.y, a3.y, va); va = fmaf(t3.z, a3.z, va); va = fmaf(t3.w, a3.w, va);
        float vb = t0.x * b0.x;
        vb = fmaf(t0.y, b0.y, vb); vb = fmaf(t0.z, b0.z, vb); vb = fmaf(t0.w, b0.w, vb);
        vb = fmaf(t1.x, b1.x, vb); vb = fmaf(t1.y, b1.y, vb); vb = fmaf(t1.z, b1.z, vb); vb = fmaf(t1.w, b1.w, vb);
        vb = fmaf(t2.x, b2.x, vb); vb = fmaf(t2.y, b2.y, vb); vb = fmaf(t2.z, b2.z, vb); vb = fmaf(t2.w, b2.w, vb);
        vb = fmaf(t3.x, b3.x, vb); vb = fmaf(t3.y, b3.y, vb); vb = fmaf(t3.z, b3.z, vb); vb = fmaf(t3.w, b3.w, vb);
        ob[s * 128 + L]      = va;   // n = eL     (L = eL*16+lm)
        ob[s * 128 + 64 + L] = vb;   // n = eL + 4
    }
}

// ---------------- last-resort fallback: direct atomics ---------------------
__global__ __launch_bounds__(128) void k_atomic(
        const float* __restrict__ distances, const float* __restrict__ dirs,
        const float* __restrict__ W, const float* __restrict__ centers,
        const int* __restrict__ zarr, const int* __restrict__ idx_i,
        const int* __restrict__ idx_j, float* __restrict__ out, int n_edges) {
    const int t = threadIdx.x;
    const int n = t >> 4, lm = t & 15;
    const int base = blockIdx.x * 8;

    __shared__ float4 gbuf[8][4];
    __shared__ float  ylm[8][16];
    __shared__ float  md[8], mfc[8], mx[8], my[8], mz[8];
    __shared__ int    ms[8], mi[8];

    const int l = (lm >= 9) ? 3 : (lm >= 4) ? 2 : (lm >= 1) ? 1 : 0;
    const float4* wp = reinterpret_cast<const float4*>(W + ((l * NMAXC + n) << 4));
    const float4 w0 = wp[0], w1 = wp[1], w2 = wp[2], w3 = wp[3];
    const float ck = centers[lm];

    if (t < 8) {
        int e = base + t;
        if (e < n_edges) {
            float d = distances[e];
            float tt = fminf(fmaxf((d - RIN_) * 2.0f, 0.0f), 1.0f);
            md[t] = d; mfc[t] = 0.5f * (cosf(PI_F * tt) + 1.0f) * (d < RCUT ? 1.f : 0.f);
            mx[t] = dirs[3 * e + 0];
            my[t] = dirs[3 * e + 1];
            mz[t] = dirs[3 * e + 2];
            ms[t] = zarr[idx_j[e]];
            mi[t] = idx_i[e];
        } else {
            md[t] = 1e9f; mfc[t] = 0.f;
            mx[t] = 0.f; my[t] = 0.f; mz[t] = 0.f; ms[t] = 0; mi[t] = 0;
        }
    }
    __syncthreads();
    {
        int e = t >> 4;
        float dd = md[e] - ck;
        reinterpret_cast<float*>(&gbuf[e][0])[lm] = __expf(-2.0f * dd * dd) * mfc[e];
    }
    {
        int e2 = t & 7, lm2 = t >> 3;
        const float* yc = &YC[lm2][0];
        float x = mx[e2], y = my[e2], z = mz[e2];
        float f1 = fmaf(yc[0], x, fmaf(yc[1], y, fmaf(yc[2], z, yc[3])));
        float f2 = fmaf(yc[4], x, fmaf(yc[5], y, fmaf(yc[6], z, yc[7])));
        float f3 = fmaf(yc[8], x, fmaf(yc[9], y, fmaf(yc[10], z, yc[11])));
        ylm[e2][lm2] = f1 * f2 * f3;
    }
    __syncthreads();
    #pragma unroll
    for (int e = 0; e < 8; ++e) {
        float4 a0 = gbuf[e][0], a1 = gbuf[e][1], a2 = gbuf[e][2], a3 = gbuf[e][3];
        float r;
        r = a0.x * w0.x;
        r = fmaf(a0.y, w0.y, r); r = fmaf(a0.z, w0.z, r); r = fmaf(a0.w, w0.w, r);
        r = fmaf(a1.x, w1.x, r); r = fmaf(a1.y, w1.y, r); r = fmaf(a1.z, w1.z, r); r = fmaf(a1.w, w1.w, r);
        r = fmaf(a2.x, w2.x, r); r = fmaf(a2.y, w2.y, r); r = fmaf(a2.z, w2.z, r); r = fmaf(a2.w, w2.w, r);
        r = fmaf(a3.x, w3.x, r); r = fmaf(a3.y, w3.y, r); r = fmaf(a3.z, w3.z, r); r = fmaf(a3.w, w3.w, r);
        float v = r * ylm[e][lm];
        int target = (mi[e] * NSPECC + ms[e]) * (NMAXC * LMC) + t;
        unsafeAtomicAdd(&out[target], v);
    }
}

// ---------------------------------------------------------------------------
extern "C" void kernel_launch(void* const* d_in, const int* in_sizes, int n_in,
                              void* d_out, int out_size, void* d_ws, size_t ws_size,
                              hipStream_t stream) {
    const float* distances = (const float*)d_in[0];
    const float* dirs      = (const float*)d_in[1];
    const float* W         = (const float*)d_in[2];
    const float* centers   = (const float*)d_in[3];
    const int*   zarr      = (const int*)d_in[4];
    const int*   idx_i     = (const int*)d_in[5];
    const int*   idx_j     = (const int*)d_in[6];
    float*       out       = (float*)d_out;

    const int n_edges = in_sizes[0];
    const int n_atoms = in_sizes[4];
    const int eb = (n_edges + 255) / 256;

    const size_t curs_b = (size_t)n_atoms * sizeof(int);                 // 80KB
    const size_t recs_b = (size_t)n_atoms * CAP * sizeof(float4);        // 41MB
    const size_t need   = curs_b + recs_b + 64;

    if (ws_size >= need) {
        int*    cursors = (int*)d_ws;
        float4* recs    = (float4*)((char*)d_ws + curs_b);
        hipMemsetAsync(cursors, 0, curs_b, stream);
        k_scat<<<eb, 256, 0, stream>>>(distances, dirs, zarr, idx_i, idx_j,
                                       cursors, recs, n_edges);
        k_mainT<<<(n_atoms + WPB - 1) / WPB, 64 * WPB, 0, stream>>>(
            recs, W, centers, cursors, out, n_atoms);
    } else {
        hipMemsetAsync(out, 0, (size_t)out_size * sizeof(float), stream);
        k_atomic<<<(n_edges + 7) / 8, 128, 0, stream>>>(distances, dirs, W, centers,
                                                        zarr, idx_i, idx_j, out, n_edges);
    }
}